// Round 4
// baseline (1364.549 us; speedup 1.0000x reference)
//
#include <hip/hip_runtime.h>

#define DM 1024
typedef unsigned short u16;
typedef __attribute__((ext_vector_type(8))) short short8;
typedef __attribute__((ext_vector_type(4))) float f32x4;

__device__ __forceinline__ float4 ldg4(const float* p) {
    return *reinterpret_cast<const float4*>(p);
}

// split f32 -> bf16 hi (truncated) + bf16 lo (residual). x ~= hi+lo, rel err ~2^-16.
__device__ __forceinline__ void split2(float x, u16& hi, u16& lo) {
    unsigned u = __float_as_uint(x);
    hi = (u16)(u >> 16);
    float hif = __uint_as_float(u & 0xffff0000u);
    lo = (u16)(__float_as_uint(x - hif) >> 16);
}

// round-to-nearest-even bf16 (inputs here are finite positive)
__device__ __forceinline__ u16 bf16rn(float x) {
    unsigned u = __float_as_uint(x);
    return (u16)((u + 0x7fffu + ((u >> 16) & 1u)) >> 16);
}

// ---------------------------------------------------------------------------
// Weight transpose+split: W[k][n] f32 -> Wt_hi[n][k], Wt_lo[n][k] bf16.
// ---------------------------------------------------------------------------
struct WPack {
    const float* in[8];
    u16* hi[8];
    u16* lo[8];
};

__global__ __launch_bounds__(256) void convw_k(WPack p) {
    __shared__ float T[32][33];
    const int w = blockIdx.y;
    const int tr = blockIdx.x >> 5, tc = blockIdx.x & 31;
    const int t = threadIdx.x;
    {
        int lr = t >> 3, c4 = t & 7;
        float4 v = ldg4(p.in[w] + (size_t)(tr * 32 + lr) * DM + tc * 32 + c4 * 4);
        T[lr][c4 * 4 + 0] = v.x; T[lr][c4 * 4 + 1] = v.y;
        T[lr][c4 * 4 + 2] = v.z; T[lr][c4 * 4 + 3] = v.w;
    }
    __syncthreads();
    const int n = tc * 32 + (t >> 3);
    const int kb = tr * 32 + (t & 7) * 4;
    ushort4 h4, l4;
    u16 hh, ll;
    split2(T[(t & 7) * 4 + 0][t >> 3], hh, ll); h4.x = hh; l4.x = ll;
    split2(T[(t & 7) * 4 + 1][t >> 3], hh, ll); h4.y = hh; l4.y = ll;
    split2(T[(t & 7) * 4 + 2][t >> 3], hh, ll); h4.z = hh; l4.z = ll;
    split2(T[(t & 7) * 4 + 3][t >> 3], hh, ll); h4.w = hh; l4.w = ll;
    *reinterpret_cast<ushort4*>(p.hi[w] + (size_t)n * DM + kb) = h4;
    *reinterpret_cast<ushort4*>(p.lo[w] + (size_t)n * DM + kb) = l4;
}

// ---------------------------------------------------------------------------
// Multi-job split-bf16 MFMA GEMM. Each job = 256 blocks (32 bm x 8 bn),
// 128x128 tile, BK=32, 4 waves. job = blockIdx.x >> 8. Runtime flags replace
// r3 templates (wave-uniform branches). NO min-waves clamp: r3's
// __launch_bounds__(256,2) capped VGPR at 128 -> inner-loop scratch spill
// (the 7x mystery). ~190 VGPR -> 2 waves/SIMD naturally, no spill.
// ---------------------------------------------------------------------------
struct GJob {
    const float* Af; const float* A2f;
    const u16* Ah; const u16* Al;
    const u16* Bh; const u16* Bl; const u16* B2h; const u16* B2l;
    const float* b1; const float* b2;
    float* Cf; u16* Ch; u16* Cl;
    int astride, aoff, nt, act, asplit, outsplit, dualk;
};
struct GJobs { GJob j[3]; };

__global__ __launch_bounds__(256) void gemm_multi(GJobs js) {
    extern __shared__ u16 lds[];
    const GJob J = js.j[blockIdx.x >> 8];
    const int bid = blockIdx.x & 255;
    const int t = threadIdx.x;
    const int r = t >> 1, h = t & 1;
    const int bm = bid >> 3, bn = bid & 7;
    const int gr = bm * 128 + r;
    const size_t arow = (size_t)(gr >> 10) * J.astride + (gr & 1023) + J.aoff;
    const size_t brow = (size_t)(bn * 128 + r);

    const int lane = t & 63, w = t >> 6;
    const int wm = w >> 1, wn = w & 1;
    const int fr = lane & 15, fk = (lane >> 4) * 8;

    f32x4 acc[4][4];
    #pragma unroll
    for (int i = 0; i < 4; ++i)
        #pragma unroll
        for (int j = 0; j < 4; ++j)
            acc[i][j] = (f32x4){0.f, 0.f, 0.f, 0.f};

    uint4 ra[4]; float4 rf[4]; uint4 rb[4];

    auto LOAD = [&](int kt) {
        int kk = kt * 32 + h * 16;
        bool second = J.dualk && (kk >= 1024);
        int kl = second ? kk - 1024 : kk;
        if (J.asplit) {
            ra[0] = *reinterpret_cast<const uint4*>(J.Ah + arow * DM + kl);
            ra[1] = *reinterpret_cast<const uint4*>(J.Ah + arow * DM + kl + 8);
            ra[2] = *reinterpret_cast<const uint4*>(J.Al + arow * DM + kl);
            ra[3] = *reinterpret_cast<const uint4*>(J.Al + arow * DM + kl + 8);
        } else {
            const float* pA = second ? J.A2f : J.Af;
            #pragma unroll
            for (int c = 0; c < 4; ++c)
                rf[c] = ldg4(pA + arow * DM + kl + c * 4);
        }
        const u16* pBh = second ? J.B2h : J.Bh;
        const u16* pBl = second ? J.B2l : J.Bl;
        rb[0] = *reinterpret_cast<const uint4*>(pBh + brow * DM + kl);
        rb[1] = *reinterpret_cast<const uint4*>(pBh + brow * DM + kl + 8);
        rb[2] = *reinterpret_cast<const uint4*>(pBl + brow * DM + kl);
        rb[3] = *reinterpret_cast<const uint4*>(pBl + brow * DM + kl + 8);
    };

    auto WRITE = [&](int buf) {
        u16* base = lds + buf * 20480;
        u16* aH = base +         r * 40 + h * 16;
        u16* aL = base +  5120 + r * 40 + h * 16;
        u16* bH = base + 10240 + r * 40 + h * 16;
        u16* bL = base + 15360 + r * 40 + h * 16;
        if (J.asplit) {
            *reinterpret_cast<uint4*>(aH) = ra[0];
            *reinterpret_cast<uint4*>(aH + 8) = ra[1];
            *reinterpret_cast<uint4*>(aL) = ra[2];
            *reinterpret_cast<uint4*>(aL + 8) = ra[3];
        } else {
            u16 hi[16], lo[16];
            float f[16] = {rf[0].x, rf[0].y, rf[0].z, rf[0].w,
                           rf[1].x, rf[1].y, rf[1].z, rf[1].w,
                           rf[2].x, rf[2].y, rf[2].z, rf[2].w,
                           rf[3].x, rf[3].y, rf[3].z, rf[3].w};
            #pragma unroll
            for (int i = 0; i < 16; ++i) split2(f[i], hi[i], lo[i]);
            #pragma unroll
            for (int q = 0; q < 2; ++q) {
                uint4 uh, ul;
                uh.x = (unsigned)hi[q*8+0] | ((unsigned)hi[q*8+1] << 16);
                uh.y = (unsigned)hi[q*8+2] | ((unsigned)hi[q*8+3] << 16);
                uh.z = (unsigned)hi[q*8+4] | ((unsigned)hi[q*8+5] << 16);
                uh.w = (unsigned)hi[q*8+6] | ((unsigned)hi[q*8+7] << 16);
                ul.x = (unsigned)lo[q*8+0] | ((unsigned)lo[q*8+1] << 16);
                ul.y = (unsigned)lo[q*8+2] | ((unsigned)lo[q*8+3] << 16);
                ul.z = (unsigned)lo[q*8+4] | ((unsigned)lo[q*8+5] << 16);
                ul.w = (unsigned)lo[q*8+6] | ((unsigned)lo[q*8+7] << 16);
                *reinterpret_cast<uint4*>(aH + q * 8) = uh;
                *reinterpret_cast<uint4*>(aL + q * 8) = ul;
            }
        }
        *reinterpret_cast<uint4*>(bH) = rb[0];
        *reinterpret_cast<uint4*>(bH + 8) = rb[1];
        *reinterpret_cast<uint4*>(bL) = rb[2];
        *reinterpret_cast<uint4*>(bL + 8) = rb[3];
    };

    auto COMPUTE = [&](int buf) {
        const u16* base = lds + buf * 20480;
        short8 ah[4], al[4];
        #pragma unroll
        for (int mi = 0; mi < 4; ++mi) {
            int ro = (wm * 64 + mi * 16 + fr) * 40 + fk;
            ah[mi] = *reinterpret_cast<const short8*>(base + ro);
            al[mi] = *reinterpret_cast<const short8*>(base + 5120 + ro);
        }
        #pragma unroll
        for (int nj = 0; nj < 4; ++nj) {
            int co = (wn * 64 + nj * 16 + fr) * 40 + fk;
            short8 bh = *reinterpret_cast<const short8*>(base + 10240 + co);
            short8 bl = *reinterpret_cast<const short8*>(base + 15360 + co);
            #pragma unroll
            for (int mi = 0; mi < 4; ++mi) {
                acc[mi][nj] = __builtin_amdgcn_mfma_f32_16x16x32_bf16(ah[mi], bh, acc[mi][nj], 0, 0, 0);
                acc[mi][nj] = __builtin_amdgcn_mfma_f32_16x16x32_bf16(ah[mi], bl, acc[mi][nj], 0, 0, 0);
                acc[mi][nj] = __builtin_amdgcn_mfma_f32_16x16x32_bf16(al[mi], bh, acc[mi][nj], 0, 0, 0);
            }
        }
    };

    const int NT = J.nt;
    LOAD(0);
    WRITE(0);
    LOAD(1);
    __syncthreads();
    for (int kt = 0; kt < NT; ++kt) {
        const int cur = kt & 1, nxt = cur ^ 1;
        if (kt + 1 < NT) WRITE(nxt);
        if (kt + 2 < NT) LOAD(kt + 2);
        COMPUTE(cur);
        __syncthreads();
    }

    // C/D frag mapping: col = lane&15, row = (lane>>4)*4 + rr (m89)
    #pragma unroll
    for (int nj = 0; nj < 4; ++nj) {
        const int col = bn * 128 + wn * 64 + nj * 16 + fr;
        float bv = J.b1[col];
        if (J.dualk) bv += J.b2[col];
        #pragma unroll
        for (int mi = 0; mi < 4; ++mi) {
            const int row0 = bm * 128 + wm * 64 + mi * 16 + (lane >> 4) * 4;
            #pragma unroll
            for (int rr = 0; rr < 4; ++rr) {
                float x = acc[mi][nj][rr] + bv;
                if (J.act == 1) x = (x >= 0.f) ? x : 0.2f * x;
                size_t off = (size_t)(row0 + rr) * DM + col;
                if (J.outsplit) {
                    u16 hh2, ll2;
                    split2(x, hh2, ll2);
                    J.Ch[off] = hh2;
                    J.Cl[off] = ll2;
                } else {
                    J.Cf[off] = x;
                }
            }
        }
    }
}

// ---------------------------------------------------------------------------
// MFMA attention. One block per (b,h,128 q-rows), 4 waves, grid 512.
// Per k-tile(128): stage K (split hi/lo) -> QK^T 3-pass MFMA (f32-accurate
// scores) -> exp in f32 (raw exp -> att global, bf16-RN -> Ps, f32 rowsum)
// -> stage V transposed (split) over K region -> PV 2-pass MFMA.
// LDS 110,080 B: Qh/Ql[128][72], (Kh/Kl[128][72] | Vth/Vtl[64][136]),
// Ps[128][136], rs[2][128], inv[128]. norm_k (unchanged) renormalizes att.
// ---------------------------------------------------------------------------
__global__ __launch_bounds__(256) void attn_mfma(
    const float* __restrict__ qp, const float* __restrict__ kp,
    const float* __restrict__ vp, const float* __restrict__ mask,
    float* __restrict__ att, float* __restrict__ omid,
    float* __restrict__ rsg)
{
    extern __shared__ u16 sm16[];
    u16* Qh  = sm16;            // [128][72]
    u16* Ql  = sm16 + 9216;
    u16* Kh  = sm16 + 18432;    // [128][72]
    u16* Kl  = sm16 + 27648;
    u16* Vth = sm16 + 18432;    // [64][136] (union with K region)
    u16* Vtl = sm16 + 27136;
    u16* Ps  = sm16 + 36864;    // [128][136]
    float* rs  = (float*)(sm16 + 54272);  // [2][128]
    float* inv = rs + 256;                // [128]

    const int t = threadIdx.x;
    const int lane = t & 63, w = t >> 6;
    const int wm = w >> 1, wn = w & 1;
    const int fr = lane & 15, fq = lane >> 4;
    const int fk = fq * 8;
    const int blk = blockIdx.x;
    const int qt = blk & 7, hh = (blk >> 3) & 15, b = blk >> 7;
    const int q0 = qt * 128;

    const size_t qbase  = ((size_t)b * 1024 + q0) * DM + hh * 64;
    const size_t kvbase = ((size_t)b * 1024) * DM + hh * 64;
    const size_t mbase  = ((size_t)b) << 20;
    const size_t abase  = ((size_t)(b * 16 + hh)) << 20;

    // stage Q once: [row][d], split hi/lo
    #pragma unroll
    for (int l = 0; l < 8; ++l) {
        int f = t + l * 256;
        int rr_ = f >> 4, dq = f & 15;
        float4 v = ldg4(qp + qbase + (size_t)rr_ * DM + dq * 4);
        u16 hi, lo; ushort4 h4, l4;
        split2(v.x, hi, lo); h4.x = hi; l4.x = lo;
        split2(v.y, hi, lo); h4.y = hi; l4.y = lo;
        split2(v.z, hi, lo); h4.z = hi; l4.z = lo;
        split2(v.w, hi, lo); h4.w = hi; l4.w = lo;
        *reinterpret_cast<ushort4*>(Qh + rr_ * 72 + dq * 4) = h4;
        *reinterpret_cast<ushort4*>(Ql + rr_ * 72 + dq * 4) = l4;
    }

    f32x4 pv[2][4];
    #pragma unroll
    for (int i = 0; i < 2; ++i)
        #pragma unroll
        for (int j = 0; j < 4; ++j)
            pv[i][j] = (f32x4){0.f, 0.f, 0.f, 0.f};
    float rpart[4][4] = {};

    for (int kt2 = 0; kt2 < 8; ++kt2) {
        const int kb = kt2 * 128;
        __syncthreads();   // prev PV reads done (K/V region reusable); Q visible (iter 0)
        // stage K tile [krow][d] split
        #pragma unroll
        for (int l = 0; l < 8; ++l) {
            int f = t + l * 256;
            int rr_ = f >> 4, dq = f & 15;
            float4 v = ldg4(kp + kvbase + (size_t)(kb + rr_) * DM + dq * 4);
            u16 hi, lo; ushort4 h4, l4;
            split2(v.x, hi, lo); h4.x = hi; l4.x = lo;
            split2(v.y, hi, lo); h4.y = hi; l4.y = lo;
            split2(v.z, hi, lo); h4.z = hi; l4.z = lo;
            split2(v.w, hi, lo); h4.w = hi; l4.w = lo;
            *reinterpret_cast<ushort4*>(Kh + rr_ * 72 + dq * 4) = h4;
            *reinterpret_cast<ushort4*>(Kl + rr_ * 72 + dq * 4) = l4;
        }
        __syncthreads();

        // QK^T: S[q][k], 3-pass split (QhKh + QhKl + QlKh), f32 accum
        f32x4 accs[4][4];
        #pragma unroll
        for (int i = 0; i < 4; ++i)
            #pragma unroll
            for (int j = 0; j < 4; ++j)
                accs[i][j] = (f32x4){0.f, 0.f, 0.f, 0.f};
        #pragma unroll
        for (int kk = 0; kk < 2; ++kk) {
            short8 qh_[4], ql_[4];
            #pragma unroll
            for (int mi = 0; mi < 4; ++mi) {
                int ro = (wm * 64 + mi * 16 + fr) * 72 + kk * 32 + fk;
                qh_[mi] = *reinterpret_cast<const short8*>(Qh + ro);
                ql_[mi] = *reinterpret_cast<const short8*>(Ql + ro);
            }
            #pragma unroll
            for (int nj = 0; nj < 4; ++nj) {
                int co = (wn * 64 + nj * 16 + fr) * 72 + kk * 32 + fk;
                short8 kh_ = *reinterpret_cast<const short8*>(Kh + co);
                short8 kl_ = *reinterpret_cast<const short8*>(Kl + co);
                #pragma unroll
                for (int mi = 0; mi < 4; ++mi) {
                    accs[mi][nj] = __builtin_amdgcn_mfma_f32_16x16x32_bf16(qh_[mi], kh_, accs[mi][nj], 0, 0, 0);
                    accs[mi][nj] = __builtin_amdgcn_mfma_f32_16x16x32_bf16(qh_[mi], kl_, accs[mi][nj], 0, 0, 0);
                    accs[mi][nj] = __builtin_amdgcn_mfma_f32_16x16x32_bf16(ql_[mi], kh_, accs[mi][nj], 0, 0, 0);
                }
            }
        }

        // exp(relu(s/8) + m*-1e9): att <- raw f32 exp; Ps <- bf16; rowsum f32
        #pragma unroll
        for (int mi = 0; mi < 4; ++mi) {
            #pragma unroll
            for (int rr = 0; rr < 4; ++rr) {
                int qrow = wm * 64 + mi * 16 + fq * 4 + rr;
                int gq = q0 + qrow;
                #pragma unroll
                for (int nj = 0; nj < 4; ++nj) {
                    int kc = wn * 64 + nj * 16 + fr;
                    float mm = mask[mbase + (size_t)gq * 1024 + kb + kc];
                    float x = fmaxf(accs[mi][nj][rr] * 0.125f, 0.f);
                    x = fmaf(mm, -1.0e9f, x);
                    float ov = __expf(x);
                    att[abase + (size_t)gq * 1024 + kb + kc] = ov;
                    Ps[qrow * 136 + kc] = bf16rn(ov);
                    rpart[mi][rr] += ov;
                }
            }
        }
        __syncthreads();   // K reads done, Ps visible

        // stage V transposed: Vt[d][k], split (overwrites K region)
        {
            int k_ = t >> 1, hd = t & 1;
            const float* src = vp + kvbase + (size_t)(kb + k_) * DM + hd * 32;
            #pragma unroll
            for (int c = 0; c < 8; ++c) {
                float4 v = ldg4(src + c * 4);
                int d0 = hd * 32 + c * 4;
                u16 hi, lo;
                split2(v.x, hi, lo); Vth[(d0+0)*136 + k_] = hi; Vtl[(d0+0)*136 + k_] = lo;
                split2(v.y, hi, lo); Vth[(d0+1)*136 + k_] = hi; Vtl[(d0+1)*136 + k_] = lo;
                split2(v.z, hi, lo); Vth[(d0+2)*136 + k_] = hi; Vtl[(d0+2)*136 + k_] = lo;
                split2(v.w, hi, lo); Vth[(d0+3)*136 + k_] = hi; Vtl[(d0+3)*136 + k_] = lo;
            }
        }
        __syncthreads();   // V visible

        // PV: out[q][d] += P[q][k] * V[k][d]; wave w owns q-strip w*32..+31
        #pragma unroll
        for (int kk = 0; kk < 4; ++kk) {
            short8 pa[2];
            #pragma unroll
            for (int mi = 0; mi < 2; ++mi) {
                int ro = (w * 32 + mi * 16 + fr) * 136 + kk * 32 + fk;
                pa[mi] = *reinterpret_cast<const short8*>(Ps + ro);
            }
            #pragma unroll
            for (int nj = 0; nj < 4; ++nj) {
                int co = (nj * 16 + fr) * 136 + kk * 32 + fk;
                short8 vh_ = *reinterpret_cast<const short8*>(Vth + co);
                short8 vl_ = *reinterpret_cast<const short8*>(Vtl + co);
                #pragma unroll
                for (int mi = 0; mi < 2; ++mi) {
                    pv[mi][nj] = __builtin_amdgcn_mfma_f32_16x16x32_bf16(pa[mi], vh_, pv[mi][nj], 0, 0, 0);
                    pv[mi][nj] = __builtin_amdgcn_mfma_f32_16x16x32_bf16(pa[mi], vl_, pv[mi][nj], 0, 0, 0);
                }
            }
        }
    }

    // rowsum: reduce across fr (16-lane groups), combine wn halves via LDS
    #pragma unroll
    for (int mi = 0; mi < 4; ++mi)
        #pragma unroll
        for (int rr = 0; rr < 4; ++rr) {
            float v = rpart[mi][rr];
            v += __shfl_xor(v, 1);
            v += __shfl_xor(v, 2);
            v += __shfl_xor(v, 4);
            v += __shfl_xor(v, 8);
            if (fr == 0) {
                int qrow = wm * 64 + mi * 16 + fq * 4 + rr;
                rs[wn * 128 + qrow] = v;
            }
        }
    __syncthreads();
    if (t < 128) {
        float iv = 1.f / (rs[t] + rs[128 + t]);
        inv[t] = iv;
        rsg[(size_t)(b * 16 + hh) * 1024 + q0 + t] = iv;
    }
    __syncthreads();

    // omid = pv * inv
    #pragma unroll
    for (int mi = 0; mi < 2; ++mi) {
        #pragma unroll
        for (int rr = 0; rr < 4; ++rr) {
            int qrow = w * 32 + mi * 16 + fq * 4 + rr;
            float iv = inv[qrow];
            #pragma unroll
            for (int nj = 0; nj < 4; ++nj) {
                omid[((size_t)b * 1024 + q0 + qrow) * DM + hh * 64 + nj * 16 + fr]
                    = pv[mi][nj][rr] * iv;
            }
        }
    }
}

// Normalize att in place (rsg holds 1/rowsum)
__global__ __launch_bounds__(256) void norm_k(
    float* __restrict__ att, const float* __restrict__ rsg)
{
    const size_t total = (size_t)67108864 / 4;
    for (size_t i = (size_t)blockIdx.x * 256 + threadIdx.x; i < total;
         i += (size_t)gridDim.x * 256) {
        float4 v = reinterpret_cast<float4*>(att)[i];
        float s = rsg[i >> 8];
        v.x *= s; v.y *= s; v.z *= s; v.w *= s;
        reinterpret_cast<float4*>(att)[i] = v;
    }
}

extern "C" void kernel_launch(void* const* d_in, const int* in_sizes, int n_in,
                              void* d_out, int out_size, void* d_ws, size_t ws_size,
                              hipStream_t stream)
{
    const float* q    = (const float*)d_in[0];
    const float* k    = (const float*)d_in[1];
    const float* v    = (const float*)d_in[2];
    const float* e    = (const float*)d_in[3];
    const float* mask = (const float*)d_in[4];
    const float* bq   = (const float*)d_in[6];
    const float* bq2  = (const float*)d_in[8];
    const float* bq3  = (const float*)d_in[10];
    const float* bk   = (const float*)d_in[12];
    const float* bk2  = (const float*)d_in[14];
    const float* bk3  = (const float*)d_in[16];
    const float* bv   = (const float*)d_in[18];
    const float* bo   = (const float*)d_in[20];

    float* out = (float*)d_out;                          // 4096*1024 f32
    float* att = out + (size_t)4096 * 1024;              // 65536*1024 f32

    // ws: 8 x (hi,lo) weights = 32MB, qp/kp/vp/omid f32, rsg
    u16* WT = (u16*)d_ws;
    const size_t WSZ = 1048576;
    float* qp   = (float*)(WT + 16 * WSZ);
    float* kp   = qp   + (size_t)4096 * 1024;
    float* vpp  = kp   + (size_t)4096 * 1024;
    float* omid = vpp  + (size_t)4096 * 1024;
    float* rsg  = omid + (size_t)4096 * 1024;

    // split intermediates live in the (not-yet-written) att region:
    // q-path and k-path get SEPARATE tmps (they run concurrently now)
    u16* tmpQH = (u16*)att;
    u16* tmpQL = tmpQH + (size_t)4096 * 1024;
    u16* tmpKH = tmpQL + (size_t)4096 * 1024;
    u16* tmpKL = tmpKH + (size_t)4096 * 1024;

    // weight conversion: Wq,Wq2,Wq3,Wk,Wk2,Wk3,Wv,Wo (inputs 5,7,..,19)
    WPack wp;
    #pragma unroll
    for (int i = 0; i < 8; ++i) {
        wp.in[i] = (const float*)d_in[5 + 2 * i];
        wp.hi[i] = WT + (size_t)i * 2 * WSZ;
        wp.lo[i] = WT + (size_t)i * 2 * WSZ + WSZ;
    }
    convw_k<<<dim3(1024, 8), 256, 0, stream>>>(wp);

    const int smemG = 81920;
    hipFuncSetAttribute((const void*)gemm_multi, hipFuncAttributeMaxDynamicSharedMemorySize, smemG);

    // Dispatch A: G1q (dual K-concat, leaky, split-out), G1k, GVv  (768 blocks)
    GJobs JA;
    JA.j[0] = GJob{q, e, nullptr, nullptr, wp.hi[0], wp.lo[0], wp.hi[1], wp.lo[1],
                   bq, bq2, nullptr, tmpQH, tmpQL, 1025, 1, 64, 1, 0, 1, 1};
    JA.j[1] = GJob{k, e, nullptr, nullptr, wp.hi[3], wp.lo[3], wp.hi[4], wp.lo[4],
                   bk, bk2, nullptr, tmpKH, tmpKL, 1025, 0, 64, 1, 0, 1, 1};
    JA.j[2] = GJob{v, nullptr, nullptr, nullptr, wp.hi[6], wp.lo[6], nullptr, nullptr,
                   bv, nullptr, vpp, nullptr, nullptr, 1024, 0, 32, 0, 0, 0, 0};
    gemm_multi<<<dim3(768), 256, smemG, stream>>>(JA);

    // Dispatch B: G2q, G2k (split-in, f32-out)  (512 blocks)
    GJobs JB;
    JB.j[0] = GJob{nullptr, nullptr, tmpQH, tmpQL, wp.hi[2], wp.lo[2], nullptr, nullptr,
                   bq3, nullptr, qp, nullptr, nullptr, 1024, 0, 32, 0, 1, 0, 0};
    JB.j[1] = GJob{nullptr, nullptr, tmpKH, tmpKL, wp.hi[5], wp.lo[5], nullptr, nullptr,
                   bk3, nullptr, kp, nullptr, nullptr, 1024, 0, 32, 0, 1, 0, 0};
    JB.j[2] = JB.j[0];
    gemm_multi<<<dim3(512), 256, smemG, stream>>>(JB);

    // attention (MFMA)
    const int smemA = 110080;
    hipFuncSetAttribute((const void*)attn_mfma, hipFuncAttributeMaxDynamicSharedMemorySize, smemA);
    attn_mfma<<<dim3(512), 256, smemA, stream>>>(qp, kp, vpp, mask, att, omid, rsg);

    // normalize att (536 MB r+w)
    norm_k<<<dim3(16384), 256, 0, stream>>>(att, rsg);

    // Dispatch C: output projection (256 blocks)
    GJobs JC;
    JC.j[0] = GJob{omid, nullptr, nullptr, nullptr, wp.hi[7], wp.lo[7], nullptr, nullptr,
                   bo, nullptr, out, nullptr, nullptr, 1024, 0, 32, 0, 0, 0, 0};
    JC.j[1] = JC.j[0];
    JC.j[2] = JC.j[0];
    gemm_multi<<<dim3(256), 256, smemG, stream>>>(JC);
}

// Round 5
// 857.499 us; speedup vs baseline: 1.5913x; 1.5913x over previous
//
#include <hip/hip_runtime.h>

#define DM 1024
typedef unsigned short u16;
typedef __attribute__((ext_vector_type(8))) short short8;
typedef __attribute__((ext_vector_type(4))) float f32x4;

__device__ __forceinline__ float4 ldg4(const float* p) {
    return *reinterpret_cast<const float4*>(p);
}

// split f32 -> bf16 hi (truncated) + bf16 lo (residual). x ~= hi+lo, rel err ~2^-16.
__device__ __forceinline__ void split2(float x, u16& hi, u16& lo) {
    unsigned u = __float_as_uint(x);
    hi = (u16)(u >> 16);
    float hif = __uint_as_float(u & 0xffff0000u);
    lo = (u16)(__float_as_uint(x - hif) >> 16);
}

// round-to-nearest-even bf16
__device__ __forceinline__ u16 bf16rn(float x) {
    unsigned u = __float_as_uint(x);
    return (u16)((u + 0x7fffu + ((u >> 16) & 1u)) >> 16);
}

// T2 swizzle: XOR the 8-u16 (16B) granule index within each 64-u16 block by row&7.
// Applied at STORE time (prep/convw/epilogues) and at ds_read time in gemm5;
// global_load_lds copies rows linearly, so LDS holds the swizzled image (m173/m201).
__device__ __forceinline__ int swzc(int row, int col) {
    return (col & ~63) | (((((col >> 3) & 7) ^ (row & 7))) << 3) | (col & 7);
}

// async global->LDS, 16B per lane (dest = uniform base + lane*16)
__device__ __forceinline__ void gl_lds16(const u16* g, u16* l) {
    __builtin_amdgcn_global_load_lds(
        (const __attribute__((address_space(1))) void*)g,
        (__attribute__((address_space(3))) void*)l, 16, 0, 0);
}

// ---------------------------------------------------------------------------
// Activation pre-split: f32 [srcrows][1024] -> swizzled split hi/lo u16.
// One block per row; thread t handles cols t*4..t*4+3 (within one granule).
// ---------------------------------------------------------------------------
struct PJob { const float* src; int astride, aoff; u16* dh; u16* dl; };
struct PJobs { PJob j[5]; };

__global__ __launch_bounds__(256) void prep_k(PJobs js) {
    const PJob J = js.j[blockIdx.x >> 12];
    const int row = blockIdx.x & 4095;
    const int t = threadIdx.x;
    const size_t srow = (size_t)(row >> 10) * J.astride + (row & 1023) + J.aoff;
    float4 v = ldg4(J.src + srow * DM + t * 4);
    u16 h[4], l[4];
    split2(v.x, h[0], l[0]); split2(v.y, h[1], l[1]);
    split2(v.z, h[2], l[2]); split2(v.w, h[3], l[3]);
    ushort4 h4 = {h[0], h[1], h[2], h[3]};
    ushort4 l4 = {l[0], l[1], l[2], l[3]};
    const int c = swzc(row, t * 4);
    *reinterpret_cast<ushort4*>(J.dh + (size_t)row * DM + c) = h4;
    *reinterpret_cast<ushort4*>(J.dl + (size_t)row * DM + c) = l4;
}

// ---------------------------------------------------------------------------
// Weight transpose+split+swizzle: W[k][n] f32 -> Wt_hi/lo[n][swzc(n,k)].
// ---------------------------------------------------------------------------
struct WPack {
    const float* in[8];
    u16* hi[8];
    u16* lo[8];
};

__global__ __launch_bounds__(256) void convw_k(WPack p) {
    __shared__ float T[32][33];
    const int w = blockIdx.y;
    const int tr = blockIdx.x >> 5, tc = blockIdx.x & 31;
    const int t = threadIdx.x;
    {
        int lr = t >> 3, c4 = t & 7;
        float4 v = ldg4(p.in[w] + (size_t)(tr * 32 + lr) * DM + tc * 32 + c4 * 4);
        T[lr][c4 * 4 + 0] = v.x; T[lr][c4 * 4 + 1] = v.y;
        T[lr][c4 * 4 + 2] = v.z; T[lr][c4 * 4 + 3] = v.w;
    }
    __syncthreads();
    const int n = tc * 32 + (t >> 3);
    const int kb = tr * 32 + (t & 7) * 4;
    ushort4 h4, l4;
    u16 hh, ll;
    split2(T[(t & 7) * 4 + 0][t >> 3], hh, ll); h4.x = hh; l4.x = ll;
    split2(T[(t & 7) * 4 + 1][t >> 3], hh, ll); h4.y = hh; l4.y = ll;
    split2(T[(t & 7) * 4 + 2][t >> 3], hh, ll); h4.z = hh; l4.z = ll;
    split2(T[(t & 7) * 4 + 3][t >> 3], hh, ll); h4.w = hh; l4.w = ll;
    const int c = swzc(n, kb);
    *reinterpret_cast<ushort4*>(p.hi[w] + (size_t)n * DM + c) = h4;
    *reinterpret_cast<ushort4*>(p.lo[w] + (size_t)n * DM + c) = l4;
}

// ---------------------------------------------------------------------------
// gemm5: m97-structure split-bf16 MFMA GEMM. 128x128 tile, BK=64, 4 waves,
// single 64KB LDS buffer, 2 barriers per K-step, global_load_lds width=16,
// swizzled LDS (conflict-free ds_read_b128). All inputs pre-split u16.
// 3 MFMA passes (AhBh + AhBl + AlBh). Multi-job: job = blockIdx.x >> 8.
// 2 blocks/CU (128KB LDS).
// ---------------------------------------------------------------------------
struct GJob {
    const u16 *Ah, *Al, *A2h, *A2l;
    const u16 *Bh, *Bl, *B2h, *B2l;
    const float *b1, *b2;
    float* Cf; u16 *Ch; u16 *Cl;
    int nt, act, outsplit, dualk;
};
struct GJobs { GJob j[3]; };

__global__ __launch_bounds__(256) void gemm5(GJobs js) {
    extern __shared__ u16 lds[];  // AH@0  AL@8192  BH@16384  BL@24576 (u16 idx)
    const GJob J = js.j[blockIdx.x >> 8];
    const int bid = blockIdx.x & 255;
    const int t = threadIdx.x;
    const int bm = bid >> 3, bn = bid & 7;
    const int lane = t & 63, w = t >> 6;
    const int wm = w >> 1, wn = w & 1;
    const int fr = lane & 15, fq = lane >> 4;

    // staging: per wave 4 gl_lds per array; lane -> (row = w*32 + i*8 + lane/8, granule = lane%7)
    const size_t ga = ((size_t)(bm * 128 + w * 32 + (lane >> 3))) * DM + (lane & 7) * 8;
    const size_t gb = ((size_t)(bn * 128 + w * 32 + (lane >> 3))) * DM + (lane & 7) * 8;

    f32x4 acc[4][4];
    #pragma unroll
    for (int i = 0; i < 4; ++i)
        #pragma unroll
        for (int j = 0; j < 4; ++j)
            acc[i][j] = (f32x4){0.f, 0.f, 0.f, 0.f};

    const int NT = J.nt;
    for (int kt = 0; kt < NT; ++kt) {
        const bool second = J.dualk && (kt >= 16);
        const int ekt = J.dualk ? (kt & 15) : kt;
        const u16* pAh = second ? J.A2h : J.Ah;
        const u16* pAl = second ? J.A2l : J.Al;
        const u16* pBh = second ? J.B2h : J.Bh;
        const u16* pBl = second ? J.B2l : J.Bl;
        const size_t ka = ga + ekt * 64;
        const size_t kb = gb + ekt * 64;

        __syncthreads();            // all waves done reading LDS from prev step
        #pragma unroll
        for (int i = 0; i < 4; ++i) {
            const int lo = w * 2048 + i * 512;      // u16 LDS offset (wave-uniform)
            const size_t go = (size_t)i * 8 * DM;
            gl_lds16(pAh + ka + go, lds +         lo);
            gl_lds16(pAl + ka + go, lds +  8192 + lo);
            gl_lds16(pBh + kb + go, lds + 16384 + lo);
            gl_lds16(pBl + kb + go, lds + 24576 + lo);
        }
        __syncthreads();            // vmcnt drained by compiler before barrier

        #pragma unroll
        for (int kk = 0; kk < 2; ++kk) {
            short8 ah[4], al[4];
            #pragma unroll
            for (int mi = 0; mi < 4; ++mi) {
                const int row = wm * 64 + mi * 16 + fr;
                const int off = row * 64 + (((kk * 4 + fq) ^ (row & 7)) << 3);
                ah[mi] = *reinterpret_cast<const short8*>(lds + off);
                al[mi] = *reinterpret_cast<const short8*>(lds + 8192 + off);
            }
            #pragma unroll
            for (int nj = 0; nj < 4; ++nj) {
                const int rb = wn * 64 + nj * 16 + fr;
                const int off = rb * 64 + (((kk * 4 + fq) ^ (rb & 7)) << 3);
                short8 bh = *reinterpret_cast<const short8*>(lds + 16384 + off);
                short8 bl = *reinterpret_cast<const short8*>(lds + 24576 + off);
                #pragma unroll
                for (int mi = 0; mi < 4; ++mi) {
                    acc[mi][nj] = __builtin_amdgcn_mfma_f32_16x16x32_bf16(ah[mi], bh, acc[mi][nj], 0, 0, 0);
                    acc[mi][nj] = __builtin_amdgcn_mfma_f32_16x16x32_bf16(ah[mi], bl, acc[mi][nj], 0, 0, 0);
                    acc[mi][nj] = __builtin_amdgcn_mfma_f32_16x16x32_bf16(al[mi], bh, acc[mi][nj], 0, 0, 0);
                }
            }
        }
    }

    // C/D frag: col = lane&15, row = (lane>>4)*4 + rr (m89)
    #pragma unroll
    for (int nj = 0; nj < 4; ++nj) {
        const int col = bn * 128 + wn * 64 + nj * 16 + fr;
        float bv = J.b1[col];
        if (J.dualk) bv += J.b2[col];
        #pragma unroll
        for (int mi = 0; mi < 4; ++mi) {
            const int row0 = bm * 128 + wm * 64 + mi * 16 + fq * 4;
            #pragma unroll
            for (int rr = 0; rr < 4; ++rr) {
                float x = acc[mi][nj][rr] + bv;
                if (J.act) x = (x >= 0.f) ? x : 0.2f * x;
                const int row = row0 + rr;
                if (J.outsplit) {
                    u16 hh, ll;
                    split2(x, hh, ll);
                    const size_t off = (size_t)row * DM + swzc(row, col);
                    J.Ch[off] = hh;
                    J.Cl[off] = ll;
                } else {
                    J.Cf[(size_t)row * DM + col] = x;
                }
            }
        }
    }
}

// ---------------------------------------------------------------------------
// attn2: MFMA attention, QBLK=64, 4 waves, grid 1024, 73KB LDS -> 2 blocks/CU.
// Per k-tile(128): stage K split -> QK^T 3-pass MFMA (f32-accurate) ->
// S bounced to LDS f32 -> COALESCED exp phase (float4 mask load, float4 att
// store, bf16 P to LDS, f32 rowsum in regs) -> stage V^T split (over S/K
// region) -> PV 2-pass MFMA. Epilogue writes omid split+swizzled for gemm5.
// ---------------------------------------------------------------------------
__global__ __launch_bounds__(256) void attn2(
    const float* __restrict__ qp, const float* __restrict__ kp,
    const float* __restrict__ vp, const float* __restrict__ mask,
    float* __restrict__ att, u16* __restrict__ omidH, u16* __restrict__ omidL,
    float* __restrict__ rsg)
{
    extern __shared__ u16 sm16[];
    u16* Qh  = sm16;                       // [64][72]
    u16* Ql  = sm16 + 4608;
    u16* Kh  = sm16 + 9216;                // [128][72]
    u16* Kl  = sm16 + 18432;
    float* Sf = (float*)(sm16 + 9216);     // [64][132] f32 (overlay on K)
    u16* Vth = sm16 + 9216;                // [64][136] (overlay on K)
    u16* Vtl = sm16 + 17920;
    u16* Ps  = sm16 + 27648;               // [64][136]
    float* rs = (float*)(sm16 + 36352);    // [64]

    const int t = threadIdx.x;
    const int lane = t & 63, w = t >> 6;
    const int wm = w >> 1, wn = w & 1;
    const int fr = lane & 15, fq = lane >> 4;
    const int blk = blockIdx.x;
    const int qt = blk & 15, hh = (blk >> 4) & 15, b = blk >> 8;
    const int q0 = qt * 64;

    const size_t qbase  = ((size_t)b * 1024 + q0) * DM + hh * 64;
    const size_t kvbase = ((size_t)b * 1024) * DM + hh * 64;
    const size_t mbase  = ((size_t)b) << 20;
    const size_t abase  = ((size_t)(b * 16 + hh)) << 20;

    // stage Q once (64 rows x 64 d), split
    #pragma unroll
    for (int l = 0; l < 4; ++l) {
        int f = t + l * 256;
        int r = f >> 4, dq = f & 15;
        float4 v = ldg4(qp + qbase + (size_t)r * DM + dq * 4);
        u16 hi, lo; ushort4 h4, l4;
        split2(v.x, hi, lo); h4.x = hi; l4.x = lo;
        split2(v.y, hi, lo); h4.y = hi; l4.y = lo;
        split2(v.z, hi, lo); h4.z = hi; l4.z = lo;
        split2(v.w, hi, lo); h4.w = hi; l4.w = lo;
        *reinterpret_cast<ushort4*>(Qh + r * 72 + dq * 4) = h4;
        *reinterpret_cast<ushort4*>(Ql + r * 72 + dq * 4) = l4;
    }

    f32x4 pv[2][2];
    #pragma unroll
    for (int i = 0; i < 2; ++i)
        #pragma unroll
        for (int j = 0; j < 2; ++j)
            pv[i][j] = (f32x4){0.f, 0.f, 0.f, 0.f};
    float rpart[8] = {};

    for (int kt2 = 0; kt2 < 8; ++kt2) {
        const int kb = kt2 * 128;
        __syncthreads();   // prev PV done (K/V/S region free); Q visible (iter 0)

        // stage K tile (128 rows x 64 d), split
        #pragma unroll
        for (int l = 0; l < 8; ++l) {
            int f = t + l * 256;
            int r = f >> 4, dq = f & 15;
            float4 v = ldg4(kp + kvbase + (size_t)(kb + r) * DM + dq * 4);
            u16 hi, lo; ushort4 h4, l4;
            split2(v.x, hi, lo); h4.x = hi; l4.x = lo;
            split2(v.y, hi, lo); h4.y = hi; l4.y = lo;
            split2(v.z, hi, lo); h4.z = hi; l4.z = lo;
            split2(v.w, hi, lo); h4.w = hi; l4.w = lo;
            *reinterpret_cast<ushort4*>(Kh + r * 72 + dq * 4) = h4;
            *reinterpret_cast<ushort4*>(Kl + r * 72 + dq * 4) = l4;
        }
        __syncthreads();

        // QK^T 3-pass: wave (wm,wn) owns q-strip 32 x k-strip 64
        f32x4 accs[2][4];
        #pragma unroll
        for (int i = 0; i < 2; ++i)
            #pragma unroll
            for (int j = 0; j < 4; ++j)
                accs[i][j] = (f32x4){0.f, 0.f, 0.f, 0.f};
        #pragma unroll
        for (int kk = 0; kk < 2; ++kk) {
            short8 qh_[2], ql_[2];
            #pragma unroll
            for (int mi = 0; mi < 2; ++mi) {
                const int off = (wm * 32 + mi * 16 + fr) * 72 + kk * 32 + fq * 8;
                qh_[mi] = *reinterpret_cast<const short8*>(Qh + off);
                ql_[mi] = *reinterpret_cast<const short8*>(Ql + off);
            }
            #pragma unroll
            for (int nj = 0; nj < 4; ++nj) {
                const int off = (wn * 64 + nj * 16 + fr) * 72 + kk * 32 + fq * 8;
                short8 kh_ = *reinterpret_cast<const short8*>(Kh + off);
                short8 kl_ = *reinterpret_cast<const short8*>(Kl + off);
                #pragma unroll
                for (int mi = 0; mi < 2; ++mi) {
                    accs[mi][nj] = __builtin_amdgcn_mfma_f32_16x16x32_bf16(qh_[mi], kh_, accs[mi][nj], 0, 0, 0);
                    accs[mi][nj] = __builtin_amdgcn_mfma_f32_16x16x32_bf16(qh_[mi], kl_, accs[mi][nj], 0, 0, 0);
                    accs[mi][nj] = __builtin_amdgcn_mfma_f32_16x16x32_bf16(ql_[mi], kh_, accs[mi][nj], 0, 0, 0);
                }
            }
        }
        __syncthreads();   // K reads done before S overwrite

        // bounce S to LDS (f32, frag-layout scatter)
        #pragma unroll
        for (int mi = 0; mi < 2; ++mi)
            #pragma unroll
            for (int rr = 0; rr < 4; ++rr) {
                const int qrow = wm * 32 + mi * 16 + fq * 4 + rr;
                #pragma unroll
                for (int nj = 0; nj < 4; ++nj)
                    Sf[qrow * 132 + wn * 64 + nj * 16 + fr] = accs[mi][nj][rr];
            }
        __syncthreads();   // S visible

        // coalesced exp phase: lane covers float4; row = (t>>5)+l*8, c4 = t&31
        #pragma unroll
        for (int l = 0; l < 8; ++l) {
            const int row = (t >> 5) + l * 8;
            const int gq = q0 + row;
            float4 sv = *reinterpret_cast<const float4*>(Sf + row * 132 + (t & 31) * 4);
            float4 mv = ldg4(mask + mbase + (size_t)gq * 1024 + kb + (t & 31) * 4);
            float e[4];
            float s4[4] = {sv.x, sv.y, sv.z, sv.w};
            float m4[4] = {mv.x, mv.y, mv.z, mv.w};
            #pragma unroll
            for (int u = 0; u < 4; ++u) {
                float x = fmaxf(s4[u] * 0.125f, 0.f);
                x = fmaf(m4[u], -1.0e9f, x);
                e[u] = __expf(x);
                rpart[l] += e[u];
            }
            float4 ev = {e[0], e[1], e[2], e[3]};
            *reinterpret_cast<float4*>(att + abase + (size_t)gq * 1024 + kb + (t & 31) * 4) = ev;
            ushort4 pp = {bf16rn(e[0]), bf16rn(e[1]), bf16rn(e[2]), bf16rn(e[3])};
            *reinterpret_cast<ushort4*>(Ps + row * 136 + (t & 31) * 4) = pp;
        }
        __syncthreads();   // S reads done before V overwrite; Ps visible

        // stage V^T (d-major), split, over S/K region
        {
            const int k_ = t >> 1, hd = t & 1;
            const float* src = vp + kvbase + (size_t)(kb + k_) * DM + hd * 32;
            #pragma unroll
            for (int c = 0; c < 8; ++c) {
                float4 v = ldg4(src + c * 4);
                const int d0 = hd * 32 + c * 4;
                u16 hi, lo;
                split2(v.x, hi, lo); Vth[(d0+0)*136 + k_] = hi; Vtl[(d0+0)*136 + k_] = lo;
                split2(v.y, hi, lo); Vth[(d0+1)*136 + k_] = hi; Vtl[(d0+1)*136 + k_] = lo;
                split2(v.z, hi, lo); Vth[(d0+2)*136 + k_] = hi; Vtl[(d0+2)*136 + k_] = lo;
                split2(v.w, hi, lo); Vth[(d0+3)*136 + k_] = hi; Vtl[(d0+3)*136 + k_] = lo;
            }
        }
        __syncthreads();   // V visible

        // PV 2-pass: wave (wm,wn) owns q-strip 32 x d-strip 32
        #pragma unroll
        for (int kk = 0; kk < 4; ++kk) {
            short8 pa[2];
            #pragma unroll
            for (int mi = 0; mi < 2; ++mi)
                pa[mi] = *reinterpret_cast<const short8*>(
                    Ps + (wm * 32 + mi * 16 + fr) * 136 + kk * 32 + fq * 8);
            #pragma unroll
            for (int nj = 0; nj < 2; ++nj) {
                const int off = (wn * 32 + nj * 16 + fr) * 136 + kk * 32 + fq * 8;
                short8 vh_ = *reinterpret_cast<const short8*>(Vth + off);
                short8 vl_ = *reinterpret_cast<const short8*>(Vtl + off);
                #pragma unroll
                for (int mi = 0; mi < 2; ++mi) {
                    pv[mi][nj] = __builtin_amdgcn_mfma_f32_16x16x32_bf16(pa[mi], vh_, pv[mi][nj], 0, 0, 0);
                    pv[mi][nj] = __builtin_amdgcn_mfma_f32_16x16x32_bf16(pa[mi], vl_, pv[mi][nj], 0, 0, 0);
                }
            }
        }
    }

    // rowsums: reduce within 32-lane groups (same row), single writer
    #pragma unroll
    for (int l = 0; l < 8; ++l) {
        float v = rpart[l];
        v += __shfl_xor(v, 1);
        v += __shfl_xor(v, 2);
        v += __shfl_xor(v, 4);
        v += __shfl_xor(v, 8);
        v += __shfl_xor(v, 16);
        if ((t & 31) == 0) rs[(t >> 5) + l * 8] = v;
    }
    __syncthreads();
    if (t < 64) {
        float iv = 1.f / rs[t];
        rs[t] = iv;
        rsg[(size_t)(b * 16 + hh) * 1024 + q0 + t] = iv;
    }
    __syncthreads();

    // omid = pv * inv, split + swizzled (k-input of the output projection)
    #pragma unroll
    for (int mi = 0; mi < 2; ++mi) {
        #pragma unroll
        for (int rr = 0; rr < 4; ++rr) {
            const int qrow = wm * 32 + mi * 16 + fq * 4 + rr;
            const float iv = rs[qrow];
            const size_t grow = (size_t)b * 1024 + q0 + qrow;
            #pragma unroll
            for (int nj = 0; nj < 2; ++nj) {
                const int d = hh * 64 + wn * 32 + nj * 16 + fr;
                float x = pv[mi][nj][rr] * iv;
                u16 hi, lo;
                split2(x, hi, lo);
                const size_t off = grow * DM + swzc(qrow, d);
                omidH[off] = hi;
                omidL[off] = lo;
            }
        }
    }
}

// Normalize att in place (rsg holds 1/rowsum)
__global__ __launch_bounds__(256) void norm_k(
    float* __restrict__ att, const float* __restrict__ rsg)
{
    const size_t total = (size_t)67108864 / 4;
    for (size_t i = (size_t)blockIdx.x * 256 + threadIdx.x; i < total;
         i += (size_t)gridDim.x * 256) {
        float4 v = reinterpret_cast<float4*>(att)[i];
        float s = rsg[i >> 8];
        v.x *= s; v.y *= s; v.z *= s; v.w *= s;
        reinterpret_cast<float4*>(att)[i] = v;
    }
}

extern "C" void kernel_launch(void* const* d_in, const int* in_sizes, int n_in,
                              void* d_out, int out_size, void* d_ws, size_t ws_size,
                              hipStream_t stream)
{
    const float* q    = (const float*)d_in[0];
    const float* k    = (const float*)d_in[1];
    const float* v    = (const float*)d_in[2];
    const float* e    = (const float*)d_in[3];
    const float* mask = (const float*)d_in[4];
    const float* bq   = (const float*)d_in[6];
    const float* bq2  = (const float*)d_in[8];
    const float* bq3  = (const float*)d_in[10];
    const float* bk   = (const float*)d_in[12];
    const float* bk2  = (const float*)d_in[14];
    const float* bk3  = (const float*)d_in[16];
    const float* bv   = (const float*)d_in[18];
    const float* bo   = (const float*)d_in[20];

    float* out = (float*)d_out;                       // 4096*1024 f32
    float* att = out + (size_t)4096 * 1024;           // 65536*1024 f32

    // ws (~96.3 MB): weights 32MB, qp/kp/vpp f32 48MB, omid split 16MB, rsg
    u16* WT = (u16*)d_ws;
    const size_t WSZ = 1048576;
    const size_t NA = (size_t)4096 * 1024;
    float* qp   = (float*)(WT + 16 * WSZ);
    float* kp   = qp + NA;
    float* vpp  = kp + NA;
    u16* omidH  = (u16*)(vpp + NA);
    u16* omidL  = omidH + NA;
    float* rsg  = (float*)(omidL + NA);

    // att-region scratch (112MB <= 268MB, all dead before attn writes att):
    u16* AR   = (u16*)att;
    u16* QspH = AR;            u16* QspL = QspH + NA;
    u16* E1H  = QspL + NA;     u16* E1L  = E1H + NA;
    u16* KspH = E1L + NA;      u16* KspL = KspH + NA;
    u16* E0H  = KspL + NA;     u16* E0L  = E0H + NA;
    u16* VsH  = E0L + NA;      u16* VsL  = VsH + NA;
    u16* tQH  = VsL + NA;      u16* tQL  = tQH + NA;
    u16* tKH  = tQL + NA;      u16* tKL  = tKH + NA;

    // activation pre-split (q rows 1.., k rows 0.., e both alignments, v)
    PJobs pj;
    pj.j[0] = PJob{q, 1025, 1, QspH, QspL};
    pj.j[1] = PJob{e, 1025, 1, E1H, E1L};
    pj.j[2] = PJob{k, 1025, 0, KspH, KspL};
    pj.j[3] = PJob{e, 1025, 0, E0H, E0L};
    pj.j[4] = PJob{v, 1024, 0, VsH, VsL};
    prep_k<<<dim3(5 * 4096), 256, 0, stream>>>(pj);

    // weight conversion: Wq,Wq2,Wq3,Wk,Wk2,Wk3,Wv,Wo
    WPack wp;
    #pragma unroll
    for (int i = 0; i < 8; ++i) {
        wp.in[i] = (const float*)d_in[5 + 2 * i];
        wp.hi[i] = WT + (size_t)i * 2 * WSZ;
        wp.lo[i] = WT + (size_t)i * 2 * WSZ + WSZ;
    }
    convw_k<<<dim3(1024, 8), 256, 0, stream>>>(wp);

    hipFuncSetAttribute((const void*)gemm5, hipFuncAttributeMaxDynamicSharedMemorySize, 65536);

    // Dispatch A: G1q (K-concat dual, leaky, split-out), G1k, GVv
    GJobs JA;
    JA.j[0] = GJob{QspH, QspL, E1H, E1L, wp.hi[0], wp.lo[0], wp.hi[1], wp.lo[1],
                   bq, bq2, nullptr, tQH, tQL, 32, 1, 1, 1};
    JA.j[1] = GJob{KspH, KspL, E0H, E0L, wp.hi[3], wp.lo[3], wp.hi[4], wp.lo[4],
                   bk, bk2, nullptr, tKH, tKL, 32, 1, 1, 1};
    JA.j[2] = GJob{VsH, VsL, nullptr, nullptr, wp.hi[6], wp.lo[6], nullptr, nullptr,
                   bv, nullptr, vpp, nullptr, nullptr, 16, 0, 0, 0};
    gemm5<<<dim3(768), 256, 65536, stream>>>(JA);

    // Dispatch B: G2q, G2k
    GJobs JB;
    JB.j[0] = GJob{tQH, tQL, nullptr, nullptr, wp.hi[2], wp.lo[2], nullptr, nullptr,
                   bq3, nullptr, qp, nullptr, nullptr, 16, 0, 0, 0};
    JB.j[1] = GJob{tKH, tKL, nullptr, nullptr, wp.hi[5], wp.lo[5], nullptr, nullptr,
                   bk3, nullptr, kp, nullptr, nullptr, 16, 0, 0, 0};
    JB.j[2] = JB.j[0];
    gemm5<<<dim3(512), 256, 65536, stream>>>(JB);

    // attention
    const int smemA = 72960;
    hipFuncSetAttribute((const void*)attn2, hipFuncAttributeMaxDynamicSharedMemorySize, smemA);
    attn2<<<dim3(1024), 256, smemA, stream>>>(qp, kp, vpp, mask, att, omidH, omidL, rsg);

    // normalize att
    norm_k<<<dim3(16384), 256, 0, stream>>>(att, rsg);

    // Dispatch C: output projection
    GJobs JC;
    JC.j[0] = GJob{omidH, omidL, nullptr, nullptr, wp.hi[7], wp.lo[7], nullptr, nullptr,
                   bo, nullptr, out, nullptr, nullptr, 16, 0, 0, 0};
    JC.j[1] = JC.j[0];
    JC.j[2] = JC.j[0];
    gemm5<<<dim3(256), 256, 65536, stream>>>(JC);
}

// Round 6
// 823.572 us; speedup vs baseline: 1.6569x; 1.0412x over previous
//
#include <hip/hip_runtime.h>

#define DM 1024
typedef unsigned short u16;
typedef __attribute__((ext_vector_type(8))) short short8;
typedef __attribute__((ext_vector_type(4))) float f32x4;

__device__ __forceinline__ float4 ldg4(const float* p) {
    return *reinterpret_cast<const float4*>(p);
}

// split f32 -> bf16 hi (truncated) + bf16 lo (residual). x ~= hi+lo, rel err ~2^-16.
__device__ __forceinline__ void split2(float x, u16& hi, u16& lo) {
    unsigned u = __float_as_uint(x);
    hi = (u16)(u >> 16);
    float hif = __uint_as_float(u & 0xffff0000u);
    lo = (u16)(__float_as_uint(x - hif) >> 16);
}

// round-to-nearest-even bf16
__device__ __forceinline__ u16 bf16rn(float x) {
    unsigned u = __float_as_uint(x);
    return (u16)((u + 0x7fffu + ((u >> 16) & 1u)) >> 16);
}

// T2 swizzle: XOR the 8-u16 (16B) granule index within each 64-u16 block by row&7.
__device__ __forceinline__ int swzc(int row, int col) {
    return (col & ~63) | (((((col >> 3) & 7) ^ (row & 7))) << 3) | (col & 7);
}

// async global->LDS, 16B per lane (dest = uniform base + lane*16)
__device__ __forceinline__ void gl_lds16(const u16* g, u16* l) {
    __builtin_amdgcn_global_load_lds(
        (const __attribute__((address_space(1))) void*)g,
        (__attribute__((address_space(3))) void*)l, 16, 0, 0);
}

// ---------------------------------------------------------------------------
// Activation pre-split: f32 [srcrows][1024] -> swizzled split hi/lo u16.
// ---------------------------------------------------------------------------
struct PJob { const float* src; int astride, aoff; u16* dh; u16* dl; };
struct PJobs { PJob j[5]; };

__global__ __launch_bounds__(256) void prep_k(PJobs js) {
    const PJob J = js.j[blockIdx.x >> 12];
    const int row = blockIdx.x & 4095;
    const int t = threadIdx.x;
    const size_t srow = (size_t)(row >> 10) * J.astride + (row & 1023) + J.aoff;
    float4 v = ldg4(J.src + srow * DM + t * 4);
    u16 h[4], l[4];
    split2(v.x, h[0], l[0]); split2(v.y, h[1], l[1]);
    split2(v.z, h[2], l[2]); split2(v.w, h[3], l[3]);
    ushort4 h4 = {h[0], h[1], h[2], h[3]};
    ushort4 l4 = {l[0], l[1], l[2], l[3]};
    const int c = swzc(row, t * 4);
    *reinterpret_cast<ushort4*>(J.dh + (size_t)row * DM + c) = h4;
    *reinterpret_cast<ushort4*>(J.dl + (size_t)row * DM + c) = l4;
}

// ---------------------------------------------------------------------------
// Weight transpose+split+swizzle: W[k][n] f32 -> Wt_hi/lo[n][swzc(n,k)].
// ---------------------------------------------------------------------------
struct WPack {
    const float* in[8];
    u16* hi[8];
    u16* lo[8];
};

__global__ __launch_bounds__(256) void convw_k(WPack p) {
    __shared__ float T[32][33];
    const int w = blockIdx.y;
    const int tr = blockIdx.x >> 5, tc = blockIdx.x & 31;
    const int t = threadIdx.x;
    {
        int lr = t >> 3, c4 = t & 7;
        float4 v = ldg4(p.in[w] + (size_t)(tr * 32 + lr) * DM + tc * 32 + c4 * 4);
        T[lr][c4 * 4 + 0] = v.x; T[lr][c4 * 4 + 1] = v.y;
        T[lr][c4 * 4 + 2] = v.z; T[lr][c4 * 4 + 3] = v.w;
    }
    __syncthreads();
    const int n = tc * 32 + (t >> 3);
    const int kb = tr * 32 + (t & 7) * 4;
    ushort4 h4, l4;
    u16 hh, ll;
    split2(T[(t & 7) * 4 + 0][t >> 3], hh, ll); h4.x = hh; l4.x = ll;
    split2(T[(t & 7) * 4 + 1][t >> 3], hh, ll); h4.y = hh; l4.y = ll;
    split2(T[(t & 7) * 4 + 2][t >> 3], hh, ll); h4.z = hh; l4.z = ll;
    split2(T[(t & 7) * 4 + 3][t >> 3], hh, ll); h4.w = hh; l4.w = ll;
    const int c = swzc(n, kb);
    *reinterpret_cast<ushort4*>(p.hi[w] + (size_t)n * DM + c) = h4;
    *reinterpret_cast<ushort4*>(p.lo[w] + (size_t)n * DM + c) = l4;
}

// ---------------------------------------------------------------------------
// gemm6: 2-PHASE pipelined split-bf16 MFMA GEMM. 128x128 tile, BK=64, 4 waves,
// DOUBLE-buffered LDS (2 x 64KB -> 1 block/CU), global_load_lds width=16,
// swizzled LDS (pre-swizzled global source). STAGE(kt+1) is issued BEFORE
// COMPUTE(kt) so next-tile loads are in flight under the MFMAs; ONE barrier
// per K-step drains them (minimum-2-phase recipe). XCD-chunked bijective
// block swizzle: 32 consecutive job-local bids per XCD -> A-panels + weight
// resident in that XCD's L2. Multi-job: job = blockIdx.x >> 8.
// ---------------------------------------------------------------------------
struct GJob {
    const u16 *Ah, *Al, *A2h, *A2l;
    const u16 *Bh, *Bl, *B2h, *B2l;
    const float *b1, *b2;
    float* Cf; u16 *Ch; u16 *Cl;
    int nt, act, outsplit, dualk;
};
struct GJobs { GJob j[3]; };

__global__ __launch_bounds__(256) void gemm6(GJobs js) {
    extern __shared__ u16 lds[];  // buf*32768 + {AH@0, AL@8192, BH@16384, BL@24576}
    const GJob J = js.j[blockIdx.x >> 8];
    const int lb = blockIdx.x & 255;
    // XCD-chunked swizzle: xcd = lb&7 gets job-local chunk of 32 blocks
    const int bid = ((lb & 7) << 5) | (lb >> 3);
    const int t = threadIdx.x;
    const int bm = bid >> 3, bn = bid & 7;
    const int lane = t & 63, w = t >> 6;
    const int wm = w >> 1, wn = w & 1;
    const int fr = lane & 15, fq = lane >> 4;

    const size_t ga = ((size_t)(bm * 128 + w * 32 + (lane >> 3))) * DM + (lane & 7) * 8;
    const size_t gb = ((size_t)(bn * 128 + w * 32 + (lane >> 3))) * DM + (lane & 7) * 8;

    f32x4 acc[4][4];
    #pragma unroll
    for (int i = 0; i < 4; ++i)
        #pragma unroll
        for (int j = 0; j < 4; ++j)
            acc[i][j] = (f32x4){0.f, 0.f, 0.f, 0.f};

    auto STAGE = [&](int kt, int buf) {
        const bool second = J.dualk && (kt >= 16);
        const int ekt = J.dualk ? (kt & 15) : kt;
        const u16* pAh = second ? J.A2h : J.Ah;
        const u16* pAl = second ? J.A2l : J.Al;
        const u16* pBh = second ? J.B2h : J.Bh;
        const u16* pBl = second ? J.B2l : J.Bl;
        const size_t ka = ga + ekt * 64;
        const size_t kb = gb + ekt * 64;
        u16* base = lds + buf * 32768;
        #pragma unroll
        for (int i = 0; i < 4; ++i) {
            const int lo = w * 2048 + i * 512;
            const size_t go = (size_t)i * 8 * DM;
            gl_lds16(pAh + ka + go, base +         lo);
            gl_lds16(pAl + ka + go, base +  8192 + lo);
            gl_lds16(pBh + kb + go, base + 16384 + lo);
            gl_lds16(pBl + kb + go, base + 24576 + lo);
        }
    };

    auto COMPUTE = [&](int buf) {
        const u16* base = lds + buf * 32768;
        #pragma unroll
        for (int kk = 0; kk < 2; ++kk) {
            short8 ah[4], al[4];
            #pragma unroll
            for (int mi = 0; mi < 4; ++mi) {
                const int row = wm * 64 + mi * 16 + fr;
                const int off = row * 64 + (((kk * 4 + fq) ^ (row & 7)) << 3);
                ah[mi] = *reinterpret_cast<const short8*>(base + off);
                al[mi] = *reinterpret_cast<const short8*>(base + 8192 + off);
            }
            #pragma unroll
            for (int nj = 0; nj < 4; ++nj) {
                const int rb = wn * 64 + nj * 16 + fr;
                const int off = rb * 64 + (((kk * 4 + fq) ^ (rb & 7)) << 3);
                short8 bh = *reinterpret_cast<const short8*>(base + 16384 + off);
                short8 bl = *reinterpret_cast<const short8*>(base + 24576 + off);
                #pragma unroll
                for (int mi = 0; mi < 4; ++mi) {
                    acc[mi][nj] = __builtin_amdgcn_mfma_f32_16x16x32_bf16(ah[mi], bh, acc[mi][nj], 0, 0, 0);
                    acc[mi][nj] = __builtin_amdgcn_mfma_f32_16x16x32_bf16(ah[mi], bl, acc[mi][nj], 0, 0, 0);
                    acc[mi][nj] = __builtin_amdgcn_mfma_f32_16x16x32_bf16(al[mi], bh, acc[mi][nj], 0, 0, 0);
                }
            }
        }
    };

    const int NT = J.nt;
    STAGE(0, 0);
    __syncthreads();                       // drain tile-0 loads
    for (int kt = 0; kt < NT; ++kt) {
        if (kt + 1 < NT) STAGE(kt + 1, (kt + 1) & 1);   // in flight under MFMAs
        COMPUTE(kt & 1);
        __syncthreads();                   // drain next-tile loads; readers done
    }

    // C/D frag: col = lane&15, row = (lane>>4)*4 + rr (m89)
    #pragma unroll
    for (int nj = 0; nj < 4; ++nj) {
        const int col = bn * 128 + wn * 64 + nj * 16 + fr;
        float bv = J.b1[col];
        if (J.dualk) bv += J.b2[col];
        #pragma unroll
        for (int mi = 0; mi < 4; ++mi) {
            const int row0 = bm * 128 + wm * 64 + mi * 16 + fq * 4;
            #pragma unroll
            for (int rr = 0; rr < 4; ++rr) {
                float x = acc[mi][nj][rr] + bv;
                if (J.act) x = (x >= 0.f) ? x : 0.2f * x;
                const int row = row0 + rr;
                if (J.outsplit) {
                    u16 hh, ll;
                    split2(x, hh, ll);
                    const size_t off = (size_t)row * DM + swzc(row, col);
                    J.Ch[off] = hh;
                    J.Cl[off] = ll;
                } else {
                    J.Cf[(size_t)row * DM + col] = x;
                }
            }
        }
    }
}

// ---------------------------------------------------------------------------
// attn2 + T14 async-stage: QBLK=64, 4 waves, grid 1024, 73KB LDS, 2 blk/CU.
// Register prefetch: K(kt+1) issued during PV; V(kt)+mask(kt) issued during
// QK^T. LDS writes happen post-barrier from registers -> the three ~600cy
// global latencies per tile hide under MFMA phases.
// ---------------------------------------------------------------------------
__global__ __launch_bounds__(256) void attn2(
    const float* __restrict__ qp, const float* __restrict__ kp,
    const float* __restrict__ vp, const float* __restrict__ mask,
    float* __restrict__ att, u16* __restrict__ omidH, u16* __restrict__ omidL,
    float* __restrict__ rsg)
{
    extern __shared__ u16 sm16[];
    u16* Qh  = sm16;                       // [64][72]
    u16* Ql  = sm16 + 4608;
    u16* Kh  = sm16 + 9216;                // [128][72]
    u16* Kl  = sm16 + 18432;
    float* Sf = (float*)(sm16 + 9216);     // [64][132] f32 (overlay on K)
    u16* Vth = sm16 + 9216;                // [64][136] (overlay on K)
    u16* Vtl = sm16 + 17920;
    u16* Ps  = sm16 + 27648;               // [64][136]
    float* rs = (float*)(sm16 + 36352);    // [64]

    const int t = threadIdx.x;
    const int lane = t & 63, w = t >> 6;
    const int wm = w >> 1, wn = w & 1;
    const int fr = lane & 15, fq = lane >> 4;
    const int blk = blockIdx.x;
    const int qt = blk & 15, hh = (blk >> 4) & 15, b = blk >> 8;
    const int q0 = qt * 64;

    const size_t qbase  = ((size_t)b * 1024 + q0) * DM + hh * 64;
    const size_t kvbase = ((size_t)b * 1024) * DM + hh * 64;
    const size_t mbase  = ((size_t)b) << 20;
    const size_t abase  = ((size_t)(b * 16 + hh)) << 20;

    // stage Q once (64 rows x 64 d), split
    #pragma unroll
    for (int l = 0; l < 4; ++l) {
        int f = t + l * 256;
        int r = f >> 4, dq = f & 15;
        float4 v = ldg4(qp + qbase + (size_t)r * DM + dq * 4);
        u16 hi, lo; ushort4 h4, l4;
        split2(v.x, hi, lo); h4.x = hi; l4.x = lo;
        split2(v.y, hi, lo); h4.y = hi; l4.y = lo;
        split2(v.z, hi, lo); h4.z = hi; l4.z = lo;
        split2(v.w, hi, lo); h4.w = hi; l4.w = lo;
        *reinterpret_cast<ushort4*>(Qh + r * 72 + dq * 4) = h4;
        *reinterpret_cast<ushort4*>(Ql + r * 72 + dq * 4) = l4;
    }

    f32x4 pv[2][2];
    #pragma unroll
    for (int i = 0; i < 2; ++i)
        #pragma unroll
        for (int j = 0; j < 2; ++j)
            pv[i][j] = (f32x4){0.f, 0.f, 0.f, 0.f};
    float rpart[8] = {};

    // prefetch K tile 0 into registers
    float4 kreg[8];
    #pragma unroll
    for (int l = 0; l < 8; ++l) {
        int f = t + l * 256;
        int r = f >> 4, dq = f & 15;
        kreg[l] = ldg4(kp + kvbase + (size_t)r * DM + dq * 4);
    }

    for (int kt2 = 0; kt2 < 8; ++kt2) {
        const int kb = kt2 * 128;
        __syncthreads();   // B1: prev PV done (K/V/S region free)

        // write K tile to LDS from kreg (split)
        #pragma unroll
        for (int l = 0; l < 8; ++l) {
            int f = t + l * 256;
            int r = f >> 4, dq = f & 15;
            float4 v = kreg[l];
            u16 hi, lo; ushort4 h4, l4;
            split2(v.x, hi, lo); h4.x = hi; l4.x = lo;
            split2(v.y, hi, lo); h4.y = hi; l4.y = lo;
            split2(v.z, hi, lo); h4.z = hi; l4.z = lo;
            split2(v.w, hi, lo); h4.w = hi; l4.w = lo;
            *reinterpret_cast<ushort4*>(Kh + r * 72 + dq * 4) = h4;
            *reinterpret_cast<ushort4*>(Kl + r * 72 + dq * 4) = l4;
        }
        __syncthreads();   // B2: K visible

        // prefetch V(kt2) + mask(kt2) into registers (land during QK^T)
        float4 vreg[8], mreg[8];
        {
            const int k_ = t >> 1, hd = t & 1;
            const float* src = vp + kvbase + (size_t)(kb + k_) * DM + hd * 32;
            #pragma unroll
            for (int c = 0; c < 8; ++c) vreg[c] = ldg4(src + c * 4);
        }
        #pragma unroll
        for (int l = 0; l < 8; ++l) {
            const int row = (t >> 5) + l * 8;
            mreg[l] = ldg4(mask + mbase + (size_t)(q0 + row) * 1024 + kb + (t & 31) * 4);
        }

        // QK^T 3-pass: wave (wm,wn) owns q-strip 32 x k-strip 64
        f32x4 accs[2][4];
        #pragma unroll
        for (int i = 0; i < 2; ++i)
            #pragma unroll
            for (int j = 0; j < 4; ++j)
                accs[i][j] = (f32x4){0.f, 0.f, 0.f, 0.f};
        #pragma unroll
        for (int kk = 0; kk < 2; ++kk) {
            short8 qh_[2], ql_[2];
            #pragma unroll
            for (int mi = 0; mi < 2; ++mi) {
                const int off = (wm * 32 + mi * 16 + fr) * 72 + kk * 32 + fq * 8;
                qh_[mi] = *reinterpret_cast<const short8*>(Qh + off);
                ql_[mi] = *reinterpret_cast<const short8*>(Ql + off);
            }
            #pragma unroll
            for (int nj = 0; nj < 4; ++nj) {
                const int off = (wn * 64 + nj * 16 + fr) * 72 + kk * 32 + fq * 8;
                short8 kh_ = *reinterpret_cast<const short8*>(Kh + off);
                short8 kl_ = *reinterpret_cast<const short8*>(Kl + off);
                #pragma unroll
                for (int mi = 0; mi < 2; ++mi) {
                    accs[mi][nj] = __builtin_amdgcn_mfma_f32_16x16x32_bf16(qh_[mi], kh_, accs[mi][nj], 0, 0, 0);
                    accs[mi][nj] = __builtin_amdgcn_mfma_f32_16x16x32_bf16(qh_[mi], kl_, accs[mi][nj], 0, 0, 0);
                    accs[mi][nj] = __builtin_amdgcn_mfma_f32_16x16x32_bf16(ql_[mi], kh_, accs[mi][nj], 0, 0, 0);
                }
            }
        }
        __syncthreads();   // B3: K reads done before S overwrite

        // bounce S to LDS (f32, frag-layout scatter)
        #pragma unroll
        for (int mi = 0; mi < 2; ++mi)
            #pragma unroll
            for (int rr = 0; rr < 4; ++rr) {
                const int qrow = wm * 32 + mi * 16 + fq * 4 + rr;
                #pragma unroll
                for (int nj = 0; nj < 4; ++nj)
                    Sf[qrow * 132 + wn * 64 + nj * 16 + fr] = accs[mi][nj][rr];
            }
        __syncthreads();   // B4: S visible

        // coalesced exp phase (mask from mreg)
        #pragma unroll
        for (int l = 0; l < 8; ++l) {
            const int row = (t >> 5) + l * 8;
            const int gq = q0 + row;
            float4 sv = *reinterpret_cast<const float4*>(Sf + row * 132 + (t & 31) * 4);
            float e[4];
            float s4[4] = {sv.x, sv.y, sv.z, sv.w};
            float m4[4] = {mreg[l].x, mreg[l].y, mreg[l].z, mreg[l].w};
            #pragma unroll
            for (int u = 0; u < 4; ++u) {
                float x = fmaxf(s4[u] * 0.125f, 0.f);
                x = fmaf(m4[u], -1.0e9f, x);
                e[u] = __expf(x);
                rpart[l] += e[u];
            }
            float4 ev = {e[0], e[1], e[2], e[3]};
            *reinterpret_cast<float4*>(att + abase + (size_t)gq * 1024 + kb + (t & 31) * 4) = ev;
            ushort4 pp = {bf16rn(e[0]), bf16rn(e[1]), bf16rn(e[2]), bf16rn(e[3])};
            *reinterpret_cast<ushort4*>(Ps + row * 136 + (t & 31) * 4) = pp;
        }
        __syncthreads();   // B5: S reads done before V overwrite; Ps visible

        // write V^T to LDS from vreg (split), over S/K region
        {
            const int k_ = t >> 1, hd = t & 1;
            #pragma unroll
            for (int c = 0; c < 8; ++c) {
                float4 v = vreg[c];
                const int d0 = hd * 32 + c * 4;
                u16 hi, lo;
                split2(v.x, hi, lo); Vth[(d0+0)*136 + k_] = hi; Vtl[(d0+0)*136 + k_] = lo;
                split2(v.y, hi, lo); Vth[(d0+1)*136 + k_] = hi; Vtl[(d0+1)*136 + k_] = lo;
                split2(v.z, hi, lo); Vth[(d0+2)*136 + k_] = hi; Vtl[(d0+2)*136 + k_] = lo;
                split2(v.w, hi, lo); Vth[(d0+3)*136 + k_] = hi; Vtl[(d0+3)*136 + k_] = lo;
            }
        }
        __syncthreads();   // B6: V visible

        // prefetch K(kt2+1) into registers (lands during PV + next B1)
        {
            const int nkb = (kt2 < 7 ? kt2 + 1 : 7) * 128;
            #pragma unroll
            for (int l = 0; l < 8; ++l) {
                int f = t + l * 256;
                int r = f >> 4, dq = f & 15;
                kreg[l] = ldg4(kp + kvbase + (size_t)(nkb + r) * DM + dq * 4);
            }
        }

        // PV 2-pass: wave (wm,wn) owns q-strip 32 x d-strip 32
        #pragma unroll
        for (int kk = 0; kk < 4; ++kk) {
            short8 pa[2];
            #pragma unroll
            for (int mi = 0; mi < 2; ++mi)
                pa[mi] = *reinterpret_cast<const short8*>(
                    Ps + (wm * 32 + mi * 16 + fr) * 136 + kk * 32 + fq * 8);
            #pragma unroll
            for (int nj = 0; nj < 2; ++nj) {
                const int off = (wn * 32 + nj * 16 + fr) * 136 + kk * 32 + fq * 8;
                short8 vh_ = *reinterpret_cast<const short8*>(Vth + off);
                short8 vl_ = *reinterpret_cast<const short8*>(Vtl + off);
                #pragma unroll
                for (int mi = 0; mi < 2; ++mi) {
                    pv[mi][nj] = __builtin_amdgcn_mfma_f32_16x16x32_bf16(pa[mi], vh_, pv[mi][nj], 0, 0, 0);
                    pv[mi][nj] = __builtin_amdgcn_mfma_f32_16x16x32_bf16(pa[mi], vl_, pv[mi][nj], 0, 0, 0);
                }
            }
        }
    }

    // rowsums: reduce within 32-lane groups (same row), single writer
    #pragma unroll
    for (int l = 0; l < 8; ++l) {
        float v = rpart[l];
        v += __shfl_xor(v, 1);
        v += __shfl_xor(v, 2);
        v += __shfl_xor(v, 4);
        v += __shfl_xor(v, 8);
        v += __shfl_xor(v, 16);
        if ((t & 31) == 0) rs[(t >> 5) + l * 8] = v;
    }
    __syncthreads();
    if (t < 64) {
        float iv = 1.f / rs[t];
        rs[t] = iv;
        rsg[(size_t)(b * 16 + hh) * 1024 + q0 + t] = iv;
    }
    __syncthreads();

    // omid = pv * inv, split + swizzled (k-input of the output projection)
    #pragma unroll
    for (int mi = 0; mi < 2; ++mi) {
        #pragma unroll
        for (int rr = 0; rr < 4; ++rr) {
            const int qrow = wm * 32 + mi * 16 + fq * 4 + rr;
            const float iv = rs[qrow];
            const size_t grow = (size_t)b * 1024 + q0 + qrow;
            #pragma unroll
            for (int nj = 0; nj < 2; ++nj) {
                const int d = hh * 64 + wn * 32 + nj * 16 + fr;
                float x = pv[mi][nj][rr] * iv;
                u16 hi, lo;
                split2(x, hi, lo);
                const size_t off = grow * DM + swzc(qrow, d);
                omidH[off] = hi;
                omidL[off] = lo;
            }
        }
    }
}

// Normalize att in place (rsg holds 1/rowsum)
__global__ __launch_bounds__(256) void norm_k(
    float* __restrict__ att, const float* __restrict__ rsg)
{
    const size_t total = (size_t)67108864 / 4;
    for (size_t i = (size_t)blockIdx.x * 256 + threadIdx.x; i < total;
         i += (size_t)gridDim.x * 256) {
        float4 v = reinterpret_cast<float4*>(att)[i];
        float s = rsg[i >> 8];
        v.x *= s; v.y *= s; v.z *= s; v.w *= s;
        reinterpret_cast<float4*>(att)[i] = v;
    }
}

extern "C" void kernel_launch(void* const* d_in, const int* in_sizes, int n_in,
                              void* d_out, int out_size, void* d_ws, size_t ws_size,
                              hipStream_t stream)
{
    const float* q    = (const float*)d_in[0];
    const float* k    = (const float*)d_in[1];
    const float* v    = (const float*)d_in[2];
    const float* e    = (const float*)d_in[3];
    const float* mask = (const float*)d_in[4];
    const float* bq   = (const float*)d_in[6];
    const float* bq2  = (const float*)d_in[8];
    const float* bq3  = (const float*)d_in[10];
    const float* bk   = (const float*)d_in[12];
    const float* bk2  = (const float*)d_in[14];
    const float* bk3  = (const float*)d_in[16];
    const float* bv   = (const float*)d_in[18];
    const float* bo   = (const float*)d_in[20];

    float* out = (float*)d_out;                       // 4096*1024 f32
    float* att = out + (size_t)4096 * 1024;           // 65536*1024 f32

    // ws: weights 32MB, qp/kp/vpp f32 48MB, omid split 16MB, rsg
    u16* WT = (u16*)d_ws;
    const size_t WSZ = 1048576;
    const size_t NA = (size_t)4096 * 1024;
    float* qp   = (float*)(WT + 16 * WSZ);
    float* kp   = qp + NA;
    float* vpp  = kp + NA;
    u16* omidH  = (u16*)(vpp + NA);
    u16* omidL  = omidH + NA;
    float* rsg  = (float*)(omidL + NA);

    // att-region scratch (112MB <= 268MB, all dead before attn writes att)
    u16* AR   = (u16*)att;
    u16* QspH = AR;            u16* QspL = QspH + NA;
    u16* E1H  = QspL + NA;     u16* E1L  = E1H + NA;
    u16* KspH = E1L + NA;      u16* KspL = KspH + NA;
    u16* E0H  = KspL + NA;     u16* E0L  = E0H + NA;
    u16* VsH  = E0L + NA;      u16* VsL  = VsH + NA;
    u16* tQH  = VsL + NA;      u16* tQL  = tQH + NA;
    u16* tKH  = tQL + NA;      u16* tKL  = tKH + NA;

    // activation pre-split
    PJobs pj;
    pj.j[0] = PJob{q, 1025, 1, QspH, QspL};
    pj.j[1] = PJob{e, 1025, 1, E1H, E1L};
    pj.j[2] = PJob{k, 1025, 0, KspH, KspL};
    pj.j[3] = PJob{e, 1025, 0, E0H, E0L};
    pj.j[4] = PJob{v, 1024, 0, VsH, VsL};
    prep_k<<<dim3(5 * 4096), 256, 0, stream>>>(pj);

    // weight conversion
    WPack wp;
    #pragma unroll
    for (int i = 0; i < 8; ++i) {
        wp.in[i] = (const float*)d_in[5 + 2 * i];
        wp.hi[i] = WT + (size_t)i * 2 * WSZ;
        wp.lo[i] = WT + (size_t)i * 2 * WSZ + WSZ;
    }
    convw_k<<<dim3(1024, 8), 256, 0, stream>>>(wp);

    hipFuncSetAttribute((const void*)gemm6, hipFuncAttributeMaxDynamicSharedMemorySize, 131072);

    // Dispatch A: G1q (K-concat dual, leaky, split-out), G1k, GVv
    GJobs JA;
    JA.j[0] = GJob{QspH, QspL, E1H, E1L, wp.hi[0], wp.lo[0], wp.hi[1], wp.lo[1],
                   bq, bq2, nullptr, tQH, tQL, 32, 1, 1, 1};
    JA.j[1] = GJob{KspH, KspL, E0H, E0L, wp.hi[3], wp.lo[3], wp.hi[4], wp.lo[4],
                   bk, bk2, nullptr, tKH, tKL, 32, 1, 1, 1};
    JA.j[2] = GJob{VsH, VsL, nullptr, nullptr, wp.hi[6], wp.lo[6], nullptr, nullptr,
                   bv, nullptr, vpp, nullptr, nullptr, 16, 0, 0, 0};
    gemm6<<<dim3(768), 256, 131072, stream>>>(JA);

    // Dispatch B: G2q, G2k
    GJobs JB;
    JB.j[0] = GJob{tQH, tQL, nullptr, nullptr, wp.hi[2], wp.lo[2], nullptr, nullptr,
                   bq3, nullptr, qp, nullptr, nullptr, 16, 0, 0, 0};
    JB.j[1] = GJob{tKH, tKL, nullptr, nullptr, wp.hi[5], wp.lo[5], nullptr, nullptr,
                   bk3, nullptr, kp, nullptr, nullptr, 16, 0, 0, 0};
    JB.j[2] = JB.j[0];
    gemm6<<<dim3(512), 256, 131072, stream>>>(JB);

    // attention
    const int smemA = 72960;
    hipFuncSetAttribute((const void*)attn2, hipFuncAttributeMaxDynamicSharedMemorySize, smemA);
    attn2<<<dim3(1024), 256, smemA, stream>>>(qp, kp, vpp, mask, att, omidH, omidL, rsg);

    // normalize att
    norm_k<<<dim3(16384), 256, 0, stream>>>(att, rsg);

    // Dispatch C: output projection
    GJobs JC;
    JC.j[0] = GJob{omidH, omidL, nullptr, nullptr, wp.hi[7], wp.lo[7], nullptr, nullptr,
                   bo, nullptr, out, nullptr, nullptr, 16, 0, 0, 0};
    JC.j[1] = JC.j[0];
    JC.j[2] = JC.j[0];
    gemm6<<<dim3(256), 256, 131072, stream>>>(JC);
}